// Round 1
// baseline (140.394 us; speedup 1.0000x reference)
//
#include <hip/hip_runtime.h>
#include <hip/hip_bf16.h>

// Edge scoring: score[e] = dot(concat(user[src[e]], item[dst[e]]), W) + b
// Nu=Ni=50000, E=320000, d0=d1=128, C=1, all fp32.
//
// Mapping: one wave (64 lanes) per edge. The 256-long concat vector is
// exactly 64 lanes x float4: lanes 0..31 cover user row (128 floats),
// lanes 32..63 cover item row. W fragment lives in registers per lane
// (W is [256,1] so lane i owns W[4i..4i+3] flat). Wave-tree reduce, lane 0
// adds bias and stores.

__global__ __launch_bounds__(256) void edge_score_kernel(
    const float* __restrict__ user_feats,
    const float* __restrict__ item_feats,
    const int*   __restrict__ src_idx,
    const int*   __restrict__ dst_idx,
    const float* __restrict__ W,
    const float* __restrict__ b,
    float*       __restrict__ out,
    int E)
{
    const int lane           = threadIdx.x & 63;
    const int wave_in_block  = threadIdx.x >> 6;
    const int waves_per_blk  = blockDim.x >> 6;
    const int global_wave    = blockIdx.x * waves_per_blk + wave_in_block;
    const int total_waves    = gridDim.x * waves_per_blk;

    // Per-lane weight fragment: W[4*lane .. 4*lane+3] (flat over the concat dim).
    const float4 w = ((const float4*)W)[lane];
    const float  bias = b[0];

    // Precompute the per-lane intra-row byte offset (16B-aligned, rows are 512B).
    const int row_elem = (lane < 32) ? (4 * lane) : (4 * (lane - 32));

    for (int e = global_wave; e < E; e += total_waves) {
        const int s = src_idx[e];
        const int d = dst_idx[e];
        const float* row = (lane < 32)
            ? (user_feats + (size_t)s * 128 + row_elem)
            : (item_feats + (size_t)d * 128 + row_elem);
        const float4 x = *(const float4*)row;

        float acc = x.x * w.x + x.y * w.y + x.z * w.z + x.w * w.w;

        // 64-lane tree reduction.
        #pragma unroll
        for (int off = 32; off > 0; off >>= 1)
            acc += __shfl_down(acc, off, 64);

        if (lane == 0) out[e] = acc + bias;
    }
}

extern "C" void kernel_launch(void* const* d_in, const int* in_sizes, int n_in,
                              void* d_out, int out_size, void* d_ws, size_t ws_size,
                              hipStream_t stream) {
    const float* user_feats = (const float*)d_in[0];
    const float* item_feats = (const float*)d_in[1];
    const int*   src_idx    = (const int*)  d_in[2];
    const int*   dst_idx    = (const int*)  d_in[3];
    const float* W          = (const float*)d_in[4];
    const float* b          = (const float*)d_in[5];
    float*       out        = (float*)d_out;

    const int E = in_sizes[2];          // edge count
    const int block = 256;              // 4 waves/block
    const int blocks = 4096;            // 16384 waves, ~20 edges/wave

    hipLaunchKernelGGL(edge_score_kernel, dim3(blocks), dim3(block), 0, stream,
                       user_feats, item_feats, src_idx, dst_idx, W, b, out, E);
}

// Round 2
// 98.408 us; speedup vs baseline: 1.4266x; 1.4266x over previous
//
#include <hip/hip_runtime.h>
#include <hip/hip_bf16.h>

// score[e] = dot(concat(user[src[e]], item[dst[e]]), W) + b with C=1
// decomposes into per-node scalar scores:
//   us[n] = dot(user_feats[n], W[0:128])
//   vs[m] = dot(item_feats[m], W[128:256])
//   score[e] = us[src[e]] + vs[dst[e]] + b
// Phase 1 streams the 51.2 MB tables once (coalesced, HBM-bound ~8.5us).
// Phase 2 gathers from two 200 KB score arrays (fits in per-XCD L2).

// Phase 1: one wave per PAIR of rows. 64 lanes x float4 = 1024 B = 2 rows
// of 128 floats. Lanes 0..31 -> row 2p, lanes 32..63 -> row 2p+1.
__global__ __launch_bounds__(256) void node_score_kernel(
    const float* __restrict__ user_feats,
    const float* __restrict__ item_feats,
    const float* __restrict__ W,
    float* __restrict__ us,
    float* __restrict__ vs,
    int Nu, int Ni)
{
    const int lane = threadIdx.x & 63;
    const int wave = (blockIdx.x * (blockDim.x >> 6)) + (threadIdx.x >> 6);

    const int upairs = (Nu + 1) >> 1;
    const int ipairs = (Ni + 1) >> 1;
    if (wave >= upairs + ipairs) return;

    const bool is_user = (wave < upairs);
    const int pair     = is_user ? wave : (wave - upairs);
    const int N        = is_user ? Nu : Ni;
    const float* feats = is_user ? user_feats : item_feats;
    float* outv        = is_user ? us : vs;

    // W fragment for this half-row: user half uses W[0:128], item half W[128:256].
    const float4 w = ((const float4*)W)[(is_user ? 0 : 32) + (lane & 31)];

    const int r0   = 2 * pair;
    const int half = lane >> 5;                 // 0 or 1
    int r = r0 + half;
    if (r >= N) r = r0;                         // keep OOB lanes in-bounds (result discarded)

    const float4 x = ((const float4*)(feats + (size_t)r * 128))[lane & 31];

    float acc = x.x * w.x + x.y * w.y + x.z * w.z + x.w * w.w;

    // Reduce within each 32-lane half (offsets 16..1 stay inside the half).
    #pragma unroll
    for (int off = 16; off > 0; off >>= 1)
        acc += __shfl_down(acc, off, 64);

    if ((lane & 31) == 0) {
        const int row = r0 + half;
        if (row < N) outv[row] = acc;
    }
}

// Phase 2: 4 edges per thread, coalesced int4 index loads, scalar gathers
// from the 200 KB score arrays (L2-resident), float4 store.
__global__ __launch_bounds__(256) void edge_combine_kernel(
    const int* __restrict__ src,
    const int* __restrict__ dst,
    const float* __restrict__ us,
    const float* __restrict__ vs,
    const float* __restrict__ b,
    float* __restrict__ out,
    int E)
{
    const int t    = blockIdx.x * blockDim.x + threadIdx.x;
    const int E4   = E >> 2;
    const float bias = b[0];

    if (t < E4) {
        const int4 s = ((const int4*)src)[t];
        const int4 d = ((const int4*)dst)[t];
        float4 o;
        o.x = us[s.x] + vs[d.x] + bias;
        o.y = us[s.y] + vs[d.y] + bias;
        o.z = us[s.z] + vs[d.z] + bias;
        o.w = us[s.w] + vs[d.w] + bias;
        ((float4*)out)[t] = o;
    }

    // Tail (E % 4 != 0): first few threads each handle one remaining edge.
    const int rem_start = E4 << 2;
    const int tail = E - rem_start;
    if (t < tail) {
        const int e = rem_start + t;
        out[e] = us[src[e]] + vs[dst[e]] + bias;
    }
}

extern "C" void kernel_launch(void* const* d_in, const int* in_sizes, int n_in,
                              void* d_out, int out_size, void* d_ws, size_t ws_size,
                              hipStream_t stream) {
    const float* user_feats = (const float*)d_in[0];
    const float* item_feats = (const float*)d_in[1];
    const int*   src_idx    = (const int*)  d_in[2];
    const int*   dst_idx    = (const int*)  d_in[3];
    const float* W          = (const float*)d_in[4];
    const float* b          = (const float*)d_in[5];
    float*       out        = (float*)d_out;

    const int Nu = in_sizes[0] / 128;
    const int Ni = in_sizes[1] / 128;
    const int E  = in_sizes[2];

    float* us = (float*)d_ws;       // Nu floats
    float* vs = us + Nu;            // Ni floats  (needs (Nu+Ni)*4 B of ws)

    // Phase 1: (Nu+1)/2 + (Ni+1)/2 waves, 4 waves per 256-thread block.
    const int waves   = ((Nu + 1) >> 1) + ((Ni + 1) >> 1);
    const int blocks1 = (waves * 64 + 255) / 256;
    hipLaunchKernelGGL(node_score_kernel, dim3(blocks1), dim3(256), 0, stream,
                       user_feats, item_feats, W, us, vs, Nu, Ni);

    // Phase 2: one thread per 4 edges (+tail).
    const int threads2 = (E >> 2) > 0 ? (E >> 2) : E;
    const int blocks2  = (threads2 + 255) / 256;
    hipLaunchKernelGGL(edge_combine_kernel, dim3(blocks2), dim3(256), 0, stream,
                       src_idx, dst_idx, us, vs, b, out, E);
}

// Round 3
// 98.135 us; speedup vs baseline: 1.4306x; 1.0028x over previous
//
#include <hip/hip_runtime.h>
#include <hip/hip_bf16.h>

// score[e] = us[src[e]] + vs[dst[e]] + b  where
//   us[n] = dot(user_feats[n], W[0:128]),  vs[m] = dot(item_feats[m], W[128:256])
// Phase 1 streams 51.2 MB coalesced (HBM floor ~8.5us); phase 2 gathers from
// two 200 KB L2-resident score arrays.
//
// R3: phase 1 restructured for memory-level parallelism — 8 row-pairs per
// wave, 8 independent dwordx4 loads in flight before the shuffle reductions
// (R2 had one 1KB load per wave -> latency-bound wave turnover).

__global__ __launch_bounds__(256) void node_score_kernel(
    const float* __restrict__ user_feats,
    const float* __restrict__ item_feats,
    const float* __restrict__ W,
    float* __restrict__ us,
    float* __restrict__ vs,
    int Nu, int Ni)
{
    constexpr int PAIRS = 8;                    // row-pairs per wave (8KB in flight)
    const int lane = threadIdx.x & 63;
    const int wave = (blockIdx.x * (blockDim.x >> 6)) + (threadIdx.x >> 6);

    const int upairs = (Nu + 1) >> 1;
    const int ipairs = (Ni + 1) >> 1;
    const int uwaves = (upairs + PAIRS - 1) / PAIRS;
    const int iwaves = (ipairs + PAIRS - 1) / PAIRS;
    if (wave >= uwaves + iwaves) return;

    const bool is_user = (wave < uwaves);
    const int wv       = is_user ? wave : (wave - uwaves);
    const int N        = is_user ? Nu : Ni;
    const float* feats = is_user ? user_feats : item_feats;
    float* outv        = is_user ? us : vs;

    // W fragment: user half uses W[0:128], item half W[128:256].
    const float4 w = ((const float4*)W)[(is_user ? 0 : 32) + (lane & 31)];

    const int pair0 = wv * PAIRS;
    const int half  = lane >> 5;                // 0 or 1 within the wave
    const int col   = lane & 31;                // float4 index within a row

    // Issue 8 independent coalesced 16B/lane loads (each pair = 1KB contiguous).
    float4 x[PAIRS];
    #pragma unroll
    for (int p = 0; p < PAIRS; ++p) {
        int r = 2 * (pair0 + p) + half;
        if (r >= N) r = N - 1;                  // clamp; result discarded below
        x[p] = ((const float4*)(feats + (size_t)r * 128))[col];
    }

    #pragma unroll
    for (int p = 0; p < PAIRS; ++p) {
        float acc = x[p].x * w.x + x[p].y * w.y + x[p].z * w.z + x[p].w * w.w;
        // Reduce within each 32-lane half.
        #pragma unroll
        for (int off = 16; off > 0; off >>= 1)
            acc += __shfl_down(acc, off, 64);
        if (col == 0) {
            const int row = 2 * (pair0 + p) + half;
            if (row < N) outv[row] = acc;
        }
    }
}

// Phase 2: 4 edges per thread, coalesced int4 index loads, scalar gathers
// from the 200 KB score arrays (L2-resident), float4 store.
__global__ __launch_bounds__(256) void edge_combine_kernel(
    const int* __restrict__ src,
    const int* __restrict__ dst,
    const float* __restrict__ us,
    const float* __restrict__ vs,
    const float* __restrict__ b,
    float* __restrict__ out,
    int E)
{
    const int t  = blockIdx.x * blockDim.x + threadIdx.x;
    const int E4 = E >> 2;
    const float bias = b[0];

    if (t < E4) {
        const int4 s = ((const int4*)src)[t];
        const int4 d = ((const int4*)dst)[t];
        float4 o;
        o.x = us[s.x] + vs[d.x] + bias;
        o.y = us[s.y] + vs[d.y] + bias;
        o.z = us[s.z] + vs[d.z] + bias;
        o.w = us[s.w] + vs[d.w] + bias;
        ((float4*)out)[t] = o;
    }

    // Tail (E % 4 != 0).
    const int rem_start = E4 << 2;
    const int tail = E - rem_start;
    if (t < tail) {
        const int e = rem_start + t;
        out[e] = us[src[e]] + vs[dst[e]] + bias;
    }
}

extern "C" void kernel_launch(void* const* d_in, const int* in_sizes, int n_in,
                              void* d_out, int out_size, void* d_ws, size_t ws_size,
                              hipStream_t stream) {
    const float* user_feats = (const float*)d_in[0];
    const float* item_feats = (const float*)d_in[1];
    const int*   src_idx    = (const int*)  d_in[2];
    const int*   dst_idx    = (const int*)  d_in[3];
    const float* W          = (const float*)d_in[4];
    const float* b          = (const float*)d_in[5];
    float*       out        = (float*)d_out;

    const int Nu = in_sizes[0] / 128;
    const int Ni = in_sizes[1] / 128;
    const int E  = in_sizes[2];

    float* us = (float*)d_ws;       // Nu floats
    float* vs = us + Nu;            // Ni floats  ((Nu+Ni)*4 B of ws used)

    constexpr int PAIRS = 8;
    const int uwaves  = (((Nu + 1) >> 1) + PAIRS - 1) / PAIRS;
    const int iwaves  = (((Ni + 1) >> 1) + PAIRS - 1) / PAIRS;
    const int waves   = uwaves + iwaves;
    const int blocks1 = (waves * 64 + 255) / 256;
    hipLaunchKernelGGL(node_score_kernel, dim3(blocks1), dim3(256), 0, stream,
                       user_feats, item_feats, W, us, vs, Nu, Ni);

    const int threads2 = (E >> 2) > 0 ? (E >> 2) : E;
    const int blocks2  = (threads2 + 255) / 256;
    hipLaunchKernelGGL(edge_combine_kernel, dim3(blocks2), dim3(256), 0, stream,
                       src_idx, dst_idx, us, vs, b, out, E);
}